// Round 9
// baseline (521.897 us; speedup 1.0000x reference)
//
#include <hip/hip_runtime.h>

#define NN 100000
#define EE 1600000
#define C 256
#define OUTC 10
#define NG 64

#define NBK 391            // ceil(NN/256) dst-buckets of 256 nodes
#define CHUNK 16384        // edges per bucket_hist/scatter block
#define NBLK1 ((EE + CHUNK - 1) / CHUNK)

#define NSL 13             // src slices: src>>13 (8192 nodes = 2MB fp8 per slice)
#define SLSH 13
#define GPW 16             // dst nodes per wave group
#define NGRP (NN / GPW)    // 6250
#define GPB (256 / GPW)    // 16 groups per bucket

typedef __bf16 bf16x8 __attribute__((ext_vector_type(8)));
typedef float f32x4 __attribute__((ext_vector_type(4)));
typedef float f32x2 __attribute__((ext_vector_type(2)));

// ---------------- bf16 helpers (RNE) ----------------
__device__ __forceinline__ ushort f2bf(float f) {
    unsigned u = __float_as_uint(f);
    return (ushort)((u + 0x7fffu + ((u >> 16) & 1u)) >> 16);
}
__device__ __forceinline__ bf16x8 as_bf16x8(uint4 v) {
    union { uint4 u; bf16x8 b; } c; c.u = v; return c.b;
}

// fp8 e4m3 encode/decode via HW converts
__device__ __forceinline__ uchar f2fp8(float f) {
    return (uchar)(__builtin_amdgcn_cvt_pk_fp8_f32(f, 0.f, 0, false) & 0xff);
}
__device__ __forceinline__ void acc_fp8x4(float4& s, unsigned v) {
    f32x2 lo = __builtin_amdgcn_cvt_pk_f32_fp8(v, false);
    f32x2 hi = __builtin_amdgcn_cvt_pk_f32_fp8(v, true);
    s.x += lo[0]; s.y += lo[1]; s.z += hi[0]; s.w += hi[1];
}

// ---------------- per-graph node counts: LDS histogram ----------------
__global__ __launch_bounds__(1024) void count_kernel(const int* __restrict__ batch,
                                                     float* __restrict__ cnt) {
    __shared__ int h[NG];
    if (threadIdx.x < NG) h[threadIdx.x] = 0;
    __syncthreads();
    int i = blockIdx.x * blockDim.x + threadIdx.x;
    if (i < NN) atomicAdd(&h[batch[i]], 1);
    __syncthreads();
    if (threadIdx.x < NG) {
        int v = h[threadIdx.x];
        if (v > 0) atomicAdd(&cnt[threadIdx.x], (float)v);
    }
}

// ---------------- bucket histogram (dst>>8), LDS-staged ----------------
__global__ __launch_bounds__(256) void bucket_hist_kernel(const int* __restrict__ ei,
                                                          int* __restrict__ bhist) {
    __shared__ int h[NBK];
    for (int t = threadIdx.x; t < NBK; t += 256) h[t] = 0;
    __syncthreads();
    const int base = blockIdx.x * CHUNK;
    const int end = min(base + CHUNK, EE);
    for (int e = base + threadIdx.x; e < end; e += 256)
        atomicAdd(&h[ei[EE + e] >> 8], 1);
    __syncthreads();
    for (int t = threadIdx.x; t < NBK; t += 256)
        if (h[t]) atomicAdd(&bhist[t], h[t]);
}

// ---------------- parallel exclusive scan of 391 bucket counts ----------------
__global__ __launch_bounds__(512) void bucket_scan_kernel(const int* __restrict__ bhist,
                                                          int* __restrict__ bbase,
                                                          int* __restrict__ bcur) {
    __shared__ int sc[512];
    const int t = threadIdx.x;
    int v = (t < NBK) ? bhist[t] : 0;
    sc[t] = v;
    __syncthreads();
    for (int off = 1; off < 512; off <<= 1) {
        int tmp = (t >= off) ? sc[t - off] : 0;
        __syncthreads();
        sc[t] += tmp;
        __syncthreads();
    }
    int excl = sc[t] - v;
    if (t < NBK) { bbase[t] = excl; bcur[t] = excl; }
    if (t == 0) bbase[NBK] = sc[511];
}

// ---------------- scatter edges into bucket-major packed records ----------------
// record = (dst & 255) << 17 | src
__global__ __launch_bounds__(256) void bucket_scatter_kernel(const int* __restrict__ ei,
                                                             int* __restrict__ bcur,
                                                             unsigned* __restrict__ bmaj) {
    __shared__ int h[NBK];
    for (int t = threadIdx.x; t < NBK; t += 256) h[t] = 0;
    __syncthreads();
    const int base = blockIdx.x * CHUNK;
    const int end = min(base + CHUNK, EE);
    for (int e = base + threadIdx.x; e < end; e += 256)
        atomicAdd(&h[ei[EE + e] >> 8], 1);
    __syncthreads();
    for (int t = threadIdx.x; t < NBK; t += 256) {
        int c = h[t];
        h[t] = c ? atomicAdd(&bcur[t], c) : 0;
    }
    __syncthreads();
    for (int e = base + threadIdx.x; e < end; e += 256) {
        int d = ei[EE + e];
        int s = ei[e];
        int b = d >> 8;
        int p = atomicAdd(&h[b], 1);
        bmaj[p] = (unsigned)s | ((unsigned)(d & 255) << 17);
    }
}

// ---------------- per-bucket: build (grp, slice, node)-ordered csr2 + E + dinv ----
// Final layout: positions are global; within a 16-node group, edges are ordered
// slice-major then node. E[grp][s][n] = END position of node n's slice-s sublist.
__global__ __launch_bounds__(256) void bucket_csr_kernel(const unsigned* __restrict__ bmaj,
                                                         const int* __restrict__ bbase,
                                                         int* __restrict__ E,
                                                         float* __restrict__ dinv,
                                                         int* __restrict__ csr2) {
    __shared__ int h[256][NSL];
    __shared__ int cur[256][NSL];
    __shared__ int cgs[GPB][NSL];
    __shared__ int segb[GPB][NSL];
    __shared__ int gbase[GPB];
    const int b = blockIdx.x;
    const int t = threadIdx.x;
    const int e0 = bbase[b], e1 = bbase[b + 1];
    const int node0 = b * 256;
    const int nvalid = min(256, NN - node0);
    const int ngv = nvalid >> 4;          // valid groups (16 or 10)

    #pragma unroll
    for (int s = 0; s < NSL; s++) h[t][s] = 0;
    __syncthreads();
    for (int e = e0 + t; e < e1; e += 256) {
        unsigned v = bmaj[e];
        atomicAdd(&h[v >> 17][(v & 0x1FFFFu) >> SLSH], 1);
    }
    __syncthreads();
    // node degree -> dinv
    if (t < nvalid) {
        int deg = 0;
        #pragma unroll
        for (int s = 0; s < NSL; s++) deg += h[t][s];
        dinv[node0 + t] = rsqrtf((float)deg + 1.0f);
    }
    // group-slice counts
    for (int idx = t; idx < ngv * NSL; idx += 256) {
        int g = idx / NSL, s = idx % NSL;
        int c = 0;
        #pragma unroll
        for (int n = 0; n < GPW; n++) c += h[g * GPW + n][s];
        cgs[g][s] = c;
    }
    __syncthreads();
    if (t == 0) {
        int acc = e0;
        for (int g = 0; g < ngv; g++) {
            gbase[g] = acc;
            for (int s = 0; s < NSL; s++) acc += cgs[g][s];
        }
    }
    __syncthreads();
    // segment starts per (g,s)
    if (t < ngv) {
        int run = gbase[t];
        for (int s = 0; s < NSL; s++) { segb[t][s] = run; run += cgs[t][s]; }
    }
    __syncthreads();
    // cur[n][s] = start of node n's slice-s sublist
    for (int idx = t; idx < ngv * NSL; idx += 256) {
        int g = idx / NSL, s = idx % NSL;
        int run = segb[g][s];
        #pragma unroll
        for (int n = 0; n < GPW; n++) {
            int nn = g * GPW + n;
            cur[nn][s] = run;
            run += h[nn][s];
        }
    }
    __syncthreads();
    // write E (ends) before scatter mutates cur
    const int grpG0 = b * GPB;
    for (int idx = t; idx < nvalid * NSL; idx += 256) {
        int nl = idx / NSL, s = idx % NSL;
        int g = nl >> 4, n = nl & 15;
        E[(((size_t)(grpG0 + g)) * NSL + s) * GPW + n] = cur[nl][s] + h[nl][s];
    }
    __syncthreads();
    // scatter
    for (int e = e0 + t; e < e1; e += 256) {
        unsigned v = bmaj[e];
        int src = (int)(v & 0x1FFFFu);
        int p = atomicAdd(&cur[v >> 17][src >> SLSH], 1);
        csr2[p] = src;
    }
}

// ---------------- W1 -> bf16 fragment-order pack ----------------
__global__ __launch_bounds__(256) void w1pack_kernel(const float* __restrict__ W1,
                                                     ushort* __restrict__ w1f) {
    int t = blockIdx.x * 256 + threadIdx.x;
    int k = t >> 8, n = t & 255;
    int kb = k >> 5, q = (k >> 3) & 3, j = k & 7;
    int nt = n >> 4, ln = (n & 15) + q * 16;
    w1f[(size_t)(((kb * 16 + nt) * 64) + ln) * 8 + j] = f2bf(W1[t]);
}

// ---------------- g = fp8((x @ W1) * dinv[row]) — MFMA, LDS-free ----------------
__global__ __launch_bounds__(256) void gemm_mfma_kernel(const float* __restrict__ x,
                                                        const ushort* __restrict__ w1f,
                                                        const float* __restrict__ dinv,
                                                        uchar* __restrict__ g) {
    const int lane = threadIdx.x & 63;
    const int wid = threadIdx.x >> 6;
    const int wave = blockIdx.x * 4 + wid;
    const int r0 = wave * 32;
    if (r0 >= NN) return;
    const int mrow = lane & 15;
    const int q = lane >> 4;

    f32x4 acc[2][16];
    #pragma unroll
    for (int mt = 0; mt < 2; mt++)
        #pragma unroll
        for (int nt = 0; nt < 16; nt++)
            acc[mt][nt] = (f32x4){0.f, 0.f, 0.f, 0.f};

    const float* xp0 = x + (size_t)(r0 + mrow) * C + q * 8;
    const float* xp1 = xp0 + (size_t)16 * C;
    const ushort* bp = w1f + (size_t)lane * 8;

    #pragma unroll 1
    for (int kb = 0; kb < 8; kb++) {
        const int ko = kb * 32;
        float4 a0lo = *(const float4*)(xp0 + ko);
        float4 a0hi = *(const float4*)(xp0 + ko + 4);
        float4 a1lo = *(const float4*)(xp1 + ko);
        float4 a1hi = *(const float4*)(xp1 + ko + 4);
        bf16x8 a0, a1;
        a0[0] = (__bf16)a0lo.x; a0[1] = (__bf16)a0lo.y;
        a0[2] = (__bf16)a0lo.z; a0[3] = (__bf16)a0lo.w;
        a0[4] = (__bf16)a0hi.x; a0[5] = (__bf16)a0hi.y;
        a0[6] = (__bf16)a0hi.z; a0[7] = (__bf16)a0hi.w;
        a1[0] = (__bf16)a1lo.x; a1[1] = (__bf16)a1lo.y;
        a1[2] = (__bf16)a1lo.z; a1[3] = (__bf16)a1lo.w;
        a1[4] = (__bf16)a1hi.x; a1[5] = (__bf16)a1hi.y;
        a1[6] = (__bf16)a1hi.z; a1[7] = (__bf16)a1hi.w;

        const ushort* bkb = bp + (size_t)kb * 16 * 512;
        #pragma unroll
        for (int nt = 0; nt < 16; nt++) {
            bf16x8 bb = as_bf16x8(*(const uint4*)(bkb + (size_t)nt * 512));
            acc[0][nt] = __builtin_amdgcn_mfma_f32_16x16x32_bf16(a0, bb, acc[0][nt], 0, 0, 0);
            acc[1][nt] = __builtin_amdgcn_mfma_f32_16x16x32_bf16(a1, bb, acc[1][nt], 0, 0, 0);
        }
    }

    #pragma unroll
    for (int mt = 0; mt < 2; mt++) {
        #pragma unroll
        for (int r = 0; r < 4; r++) {
            int row = r0 + mt * 16 + q * 4 + r;
            float dv = dinv[row];
            uchar* gp = g + (size_t)row * C + mrow;
            #pragma unroll
            for (int nt = 0; nt < 16; nt++)
                gp[nt * 16] = f2fp8(acc[mt][nt][r] * dv);
        }
    }
}

// ---------------- aggregate + relu + mean-pool, slice-synchronized gather ----------
// Wave owns 16 dst nodes. Outer loop over 13 src slices keeps the chip-wide
// gather working set ~2MB (fits per-XCD L2). Indices vector-loaded 64/chunk,
// broadcast via readlane (scalar pipe, no DS). Accumulators static-indexed.
__global__ __launch_bounds__(256) void agg_pool_kernel(const unsigned* __restrict__ g32,
                                                       const int* __restrict__ E,
                                                       const int* __restrict__ csr2,
                                                       const float* __restrict__ dinv,
                                                       const float* __restrict__ b1,
                                                       const int* __restrict__ batch,
                                                       float* __restrict__ sums) {
    const int lane = threadIdx.x & 63;
    const int wid = threadIdx.x >> 6;
    const int grp = blockIdx.x * 4 + wid;
    if (grp >= NGRP) return;
    const int c4 = lane * 4;
    const int node0 = grp * GPW;

    float4 acc[GPW];
    #pragma unroll
    for (int n = 0; n < GPW; n++) acc[n] = make_float4(0.f, 0.f, 0.f, 0.f);

    int p = (grp == 0) ? 0 : E[(((size_t)(grp - 1)) * NSL + (NSL - 1)) * GPW + (GPW - 1)];

    #pragma unroll 1
    for (int s = 0; s < NSL; s++) {
        int eb[GPW];
        const int* Ep = E + (((size_t)grp) * NSL + s) * GPW;
        *(int4*)&eb[0]  = *(const int4*)(Ep + 0);
        *(int4*)&eb[4]  = *(const int4*)(Ep + 4);
        *(int4*)&eb[8]  = *(const int4*)(Ep + 8);
        *(int4*)&eb[12] = *(const int4*)(Ep + 12);
        const int segbase = p;
        const int cnt = eb[GPW - 1] - segbase;
        #pragma unroll 1
        for (int kb = 0; kb < cnt; kb += 64) {
            int rec = 0;
            if (kb + lane < cnt) rec = csr2[segbase + kb + lane];
            const int chunk_end = segbase + min(kb + 64, cnt);
            #pragma unroll
            for (int n = 0; n < GPW; n++) {
                int lim = min(eb[n], chunk_end);
                while (p < lim) {
                    int idx = __builtin_amdgcn_readlane(rec, p - segbase - kb);
                    acc_fp8x4(acc[n], g32[(size_t)idx * 64 + lane]);
                    p++;
                }
            }
        }
    }

    // finalize: self-loop, norm, bias, relu, pool, per-graph flush
    const float4 bv = *(const float4*)&b1[c4];
    float4 pool = make_float4(0.f, 0.f, 0.f, 0.f);
    int curb = -1;
    #pragma unroll
    for (int n = 0; n < GPW; n++) {
        int i = node0 + n;
        int bi = batch[i];
        if (bi != curb) {
            if (curb >= 0) {
                atomicAdd(&sums[curb * C + c4 + 0], pool.x);
                atomicAdd(&sums[curb * C + c4 + 1], pool.y);
                atomicAdd(&sums[curb * C + c4 + 2], pool.z);
                atomicAdd(&sums[curb * C + c4 + 3], pool.w);
            }
            curb = bi;
            pool = make_float4(0.f, 0.f, 0.f, 0.f);
        }
        float4 sv = acc[n];
        acc_fp8x4(sv, g32[(size_t)i * 64 + lane]);    // self-loop
        float dv = dinv[i];
        pool.x += fmaxf(fmaf(dv, sv.x, bv.x), 0.f);
        pool.y += fmaxf(fmaf(dv, sv.y, bv.y), 0.f);
        pool.z += fmaxf(fmaf(dv, sv.z, bv.z), 0.f);
        pool.w += fmaxf(fmaf(dv, sv.w, bv.w), 0.f);
    }
    if (curb >= 0) {
        atomicAdd(&sums[curb * C + c4 + 0], pool.x);
        atomicAdd(&sums[curb * C + c4 + 1], pool.y);
        atomicAdd(&sums[curb * C + c4 + 2], pool.z);
        atomicAdd(&sums[curb * C + c4 + 3], pool.w);
    }
}

// ---------------- pooled = sums/cnt; out = pooled @ W2 + b2 ----------------
__global__ __launch_bounds__(256) void final_kernel(const float* __restrict__ sums,
                                                    const float* __restrict__ cnt,
                                                    const float* __restrict__ W2,
                                                    const float* __restrict__ b2,
                                                    float* __restrict__ out) {
    __shared__ float p[C];
    int gi = blockIdx.x;
    float cdiv = fmaxf(cnt[gi], 1.0f);
    p[threadIdx.x] = sums[gi * C + threadIdx.x] / cdiv;
    __syncthreads();
    if (threadIdx.x < OUTC) {
        float acc = b2[threadIdx.x];
        for (int k = 0; k < C; k++) acc += p[k] * W2[k * OUTC + threadIdx.x];
        out[gi * OUTC + threadIdx.x] = acc;
    }
}

extern "C" void kernel_launch(void* const* d_in, const int* in_sizes, int n_in,
                              void* d_out, int out_size, void* d_ws, size_t ws_size,
                              hipStream_t stream) {
    const float* x     = (const float*)d_in[0];
    const int*   ei    = (const int*)d_in[1];
    const int*   batch = (const int*)d_in[2];
    const float* W1    = (const float*)d_in[3];
    const float* b1    = (const float*)d_in[4];
    const float* W2    = (const float*)d_in[5];
    const float* b2    = (const float*)d_in[6];
    float* out = (float*)d_out;

    char* w = (char*)d_ws;
    size_t off = 0;
    auto carve = [&](size_t bytes) {
        void* p = w + off;
        off = (off + bytes + 255) & ~(size_t)255;
        return p;
    };
    uchar*    g        = (uchar*)   carve((size_t)NN * C);        // fp8 e4m3
    float*    dinv     = (float*)   carve((size_t)NN * 4);
    int*      csr2     = (int*)     carve((size_t)EE * 4);
    unsigned* bmaj     = (unsigned*)carve((size_t)EE * 4);
    int*      Earr     = (int*)     carve((size_t)NGRP * NSL * GPW * 4);
    int*      bbase    = (int*)     carve((size_t)(NBK + 1) * 4);
    int*      bcur     = (int*)     carve((size_t)NBK * 4);
    ushort*   w1f      = (ushort*)  carve((size_t)C * C * 2);
    // contiguous zero-init region:
    int*      bhist    = (int*)     carve((size_t)NBK * 4);
    float*    sums     = (float*)   carve((size_t)NG * C * 4);
    float*    cnt      = (float*)   carve((size_t)NG * 4);
    size_t zero_bytes = (size_t)((char*)cnt + (size_t)NG * 4 - (char*)bhist);

    hipMemsetAsync(bhist, 0, zero_bytes, stream);

    bucket_hist_kernel<<<NBLK1, 256, 0, stream>>>(ei, bhist);
    bucket_scan_kernel<<<1, 512, 0, stream>>>(bhist, bbase, bcur);
    bucket_scatter_kernel<<<NBLK1, 256, 0, stream>>>(ei, bcur, bmaj);
    bucket_csr_kernel<<<NBK, 256, 0, stream>>>(bmaj, bbase, Earr, dinv, csr2);
    count_kernel<<<(NN + 1023) / 1024, 1024, 0, stream>>>(batch, cnt);
    w1pack_kernel<<<C * C / 256, 256, 0, stream>>>(W1, w1f);
    gemm_mfma_kernel<<<(NN / 32 + 3) / 4, 256, 0, stream>>>(x, w1f, dinv, g);
    agg_pool_kernel<<<(NGRP + 3) / 4, 256, 0, stream>>>(
        (const unsigned*)g, Earr, csr2, dinv, b1, batch, sums);
    final_kernel<<<NG, 256, 0, stream>>>(sums, cnt, W2, b2, out);
}

// Round 10
// 423.953 us; speedup vs baseline: 1.2310x; 1.2310x over previous
//
#include <hip/hip_runtime.h>

#define NN 100000
#define EE 1600000
#define C 256
#define OUTC 10
#define NG 64

#define NBK 391            // ceil(NN/256) dst-buckets of 256 nodes
#define CHUNK 16384        // edges per bucket_hist/scatter block
#define NBLK1 ((EE + CHUNK - 1) / CHUNK)
#define PADSLACK 2048      // per-bucket csrcol slack: 256 nodes * 7 max pad < 2048

// agg_pool decomposition: 4 waves/block, each wave owns NODES_PER_GROUP nodes
#define NODES_PER_GROUP 8
#define NODES_PER_BLOCK 32      // 100000 = 32 * 3125 exactly

typedef __bf16 bf16x8 __attribute__((ext_vector_type(8)));
typedef float f32x4 __attribute__((ext_vector_type(4)));
typedef float f32x2 __attribute__((ext_vector_type(2)));

// ---------------- bf16 helpers (RNE) ----------------
__device__ __forceinline__ ushort f2bf(float f) {
    unsigned u = __float_as_uint(f);
    return (ushort)((u + 0x7fffu + ((u >> 16) & 1u)) >> 16);
}
__device__ __forceinline__ bf16x8 as_bf16x8(uint4 v) {
    union { uint4 u; bf16x8 b; } c; c.u = v; return c.b;
}

// fp8 e4m3 encode/decode via HW converts
__device__ __forceinline__ uchar f2fp8(float f) {
    return (uchar)(__builtin_amdgcn_cvt_pk_fp8_f32(f, 0.f, 0, false) & 0xff);
}
__device__ __forceinline__ void acc_fp8x4(float4& s, unsigned v) {
    f32x2 lo = __builtin_amdgcn_cvt_pk_f32_fp8(v, false);
    f32x2 hi = __builtin_amdgcn_cvt_pk_f32_fp8(v, true);
    s.x += lo[0]; s.y += lo[1]; s.z += hi[0]; s.w += hi[1];
}

// ---------------- per-graph node counts: LDS histogram ----------------
__global__ __launch_bounds__(1024) void count_kernel(const int* __restrict__ batch,
                                                     float* __restrict__ cnt) {
    __shared__ int h[NG];
    if (threadIdx.x < NG) h[threadIdx.x] = 0;
    __syncthreads();
    int i = blockIdx.x * blockDim.x + threadIdx.x;
    if (i < NN) atomicAdd(&h[batch[i]], 1);
    __syncthreads();
    if (threadIdx.x < NG) {
        int v = h[threadIdx.x];
        if (v > 0) atomicAdd(&cnt[threadIdx.x], (float)v);
    }
}

// ---------------- bucket histogram (dst>>8), LDS-staged ----------------
__global__ __launch_bounds__(256) void bucket_hist_kernel(const int* __restrict__ ei,
                                                          int* __restrict__ bhist) {
    __shared__ int h[NBK];
    for (int t = threadIdx.x; t < NBK; t += 256) h[t] = 0;
    __syncthreads();
    const int base = blockIdx.x * CHUNK;
    const int end = min(base + CHUNK, EE);
    for (int e = base + threadIdx.x; e < end; e += 256)
        atomicAdd(&h[ei[EE + e] >> 8], 1);
    __syncthreads();
    for (int t = threadIdx.x; t < NBK; t += 256)
        if (h[t]) atomicAdd(&bhist[t], h[t]);
}

// ---------------- parallel exclusive scan of 391 bucket counts ----------------
__global__ __launch_bounds__(512) void bucket_scan_kernel(const int* __restrict__ bhist,
                                                          int* __restrict__ bbase,
                                                          int* __restrict__ bcur) {
    __shared__ int sc[512];
    const int t = threadIdx.x;
    int v = (t < NBK) ? bhist[t] : 0;
    sc[t] = v;
    __syncthreads();
    for (int off = 1; off < 512; off <<= 1) {
        int tmp = (t >= off) ? sc[t - off] : 0;
        __syncthreads();
        sc[t] += tmp;
        __syncthreads();
    }
    int excl = sc[t] - v;
    if (t < NBK) { bbase[t] = excl; bcur[t] = excl; }
    if (t == 0) bbase[NBK] = sc[511];
}

// ---------------- scatter edges into bucket-major packed records ----------------
// record = (dst & 255) << 17 | src
__global__ __launch_bounds__(256) void bucket_scatter_kernel(const int* __restrict__ ei,
                                                             int* __restrict__ bcur,
                                                             unsigned* __restrict__ bmaj) {
    __shared__ int h[NBK];
    for (int t = threadIdx.x; t < NBK; t += 256) h[t] = 0;
    __syncthreads();
    const int base = blockIdx.x * CHUNK;
    const int end = min(base + CHUNK, EE);
    for (int e = base + threadIdx.x; e < end; e += 256)
        atomicAdd(&h[ei[EE + e] >> 8], 1);
    __syncthreads();
    for (int t = threadIdx.x; t < NBK; t += 256) {
        int c = h[t];
        h[t] = c ? atomicAdd(&bcur[t], c) : 0;
    }
    __syncthreads();
    for (int e = base + threadIdx.x; e < end; e += 256) {
        int d = ei[EE + e];
        int s = ei[e];
        int b = d >> 8;
        int p = atomicAdd(&h[b], 1);
        bmaj[p] = (unsigned)s | ((unsigned)(d & 255) << 17);
    }
}

// ---------------- per-bucket: degree, PADDED rowend, dinv, dense csrcol ----------
// Node lists padded to multiple of 8 with sentinel index NN (zero g-row).
// Bucket b's csrcol region starts at bbase[b] + b*PADSLACK.
__global__ __launch_bounds__(256) void bucket_csr_kernel(const unsigned* __restrict__ bmaj,
                                                         const int* __restrict__ bbase,
                                                         int* __restrict__ rowend,
                                                         float* __restrict__ dinv,
                                                         int* __restrict__ csrcol) {
    __shared__ int h[256];
    __shared__ int sc[256];
    __shared__ int cur[256];
    const int b = blockIdx.x;
    const int t = threadIdx.x;
    const int e0 = bbase[b], e1 = bbase[b + 1];
    const int region0 = e0 + b * PADSLACK;
    h[t] = 0;
    __syncthreads();
    for (int e = e0 + t; e < e1; e += 256)
        atomicAdd(&h[bmaj[e] >> 17], 1);
    __syncthreads();
    int deg = h[t];
    int pd = (deg + 7) & ~7;               // padded degree
    sc[t] = pd;
    __syncthreads();
    for (int off = 1; off < 256; off <<= 1) {
        int tmp = (t >= off) ? sc[t - off] : 0;
        __syncthreads();
        sc[t] += tmp;
        __syncthreads();
    }
    int pstart = region0 + sc[t] - pd;
    int node = b * 256 + t;
    if (node < NN) {
        rowend[node] = pstart + pd;        // PADDED end
        dinv[node] = rsqrtf((float)deg + 1.0f);
        for (int j = deg; j < pd; j++) csrcol[pstart + j] = NN;   // sentinels
    }
    cur[t] = pstart;
    __syncthreads();
    for (int e = e0 + t; e < e1; e += 256) {
        unsigned v = bmaj[e];
        int p = atomicAdd(&cur[v >> 17], 1);
        csrcol[p] = (int)(v & 0x1FFFFu);
    }
}

// ---------------- W1 -> bf16 fragment-order pack (+ zero sentinel g-row) --------
__global__ __launch_bounds__(256) void w1pack_kernel(const float* __restrict__ W1,
                                                     ushort* __restrict__ w1f,
                                                     unsigned* __restrict__ gz) {
    int t = blockIdx.x * 256 + threadIdx.x;
    if (blockIdx.x == 0 && threadIdx.x < 64) gz[threadIdx.x] = 0;   // g row NN = 0
    int k = t >> 8, n = t & 255;
    int kb = k >> 5, q = (k >> 3) & 3, j = k & 7;
    int nt = n >> 4, ln = (n & 15) + q * 16;
    w1f[(size_t)(((kb * 16 + nt) * 64) + ln) * 8 + j] = f2bf(W1[t]);
}

// ---------------- g = fp8((x @ W1) * dinv[row]) — MFMA, LDS-free ----------------
__global__ __launch_bounds__(256) void gemm_mfma_kernel(const float* __restrict__ x,
                                                        const ushort* __restrict__ w1f,
                                                        const float* __restrict__ dinv,
                                                        uchar* __restrict__ g) {
    const int lane = threadIdx.x & 63;
    const int wid = threadIdx.x >> 6;
    const int wave = blockIdx.x * 4 + wid;
    const int r0 = wave * 32;
    if (r0 >= NN) return;
    const int mrow = lane & 15;
    const int q = lane >> 4;

    f32x4 acc[2][16];
    #pragma unroll
    for (int mt = 0; mt < 2; mt++)
        #pragma unroll
        for (int nt = 0; nt < 16; nt++)
            acc[mt][nt] = (f32x4){0.f, 0.f, 0.f, 0.f};

    const float* xp0 = x + (size_t)(r0 + mrow) * C + q * 8;
    const float* xp1 = xp0 + (size_t)16 * C;
    const ushort* bp = w1f + (size_t)lane * 8;

    #pragma unroll 1
    for (int kb = 0; kb < 8; kb++) {
        const int ko = kb * 32;
        float4 a0lo = *(const float4*)(xp0 + ko);
        float4 a0hi = *(const float4*)(xp0 + ko + 4);
        float4 a1lo = *(const float4*)(xp1 + ko);
        float4 a1hi = *(const float4*)(xp1 + ko + 4);
        bf16x8 a0, a1;
        a0[0] = (__bf16)a0lo.x; a0[1] = (__bf16)a0lo.y;
        a0[2] = (__bf16)a0lo.z; a0[3] = (__bf16)a0lo.w;
        a0[4] = (__bf16)a0hi.x; a0[5] = (__bf16)a0hi.y;
        a0[6] = (__bf16)a0hi.z; a0[7] = (__bf16)a0hi.w;
        a1[0] = (__bf16)a1lo.x; a1[1] = (__bf16)a1lo.y;
        a1[2] = (__bf16)a1lo.z; a1[3] = (__bf16)a1lo.w;
        a1[4] = (__bf16)a1hi.x; a1[5] = (__bf16)a1hi.y;
        a1[6] = (__bf16)a1hi.z; a1[7] = (__bf16)a1hi.w;

        const ushort* bkb = bp + (size_t)kb * 16 * 512;
        #pragma unroll
        for (int nt = 0; nt < 16; nt++) {
            bf16x8 bb = as_bf16x8(*(const uint4*)(bkb + (size_t)nt * 512));
            acc[0][nt] = __builtin_amdgcn_mfma_f32_16x16x32_bf16(a0, bb, acc[0][nt], 0, 0, 0);
            acc[1][nt] = __builtin_amdgcn_mfma_f32_16x16x32_bf16(a1, bb, acc[1][nt], 0, 0, 0);
        }
    }

    #pragma unroll
    for (int mt = 0; mt < 2; mt++) {
        #pragma unroll
        for (int r = 0; r < 4; r++) {
            int row = r0 + mt * 16 + q * 4 + r;
            float dv = dinv[row];
            uchar* gp = g + (size_t)row * C + mrow;
            #pragma unroll
            for (int nt = 0; nt < 16; nt++)
                gp[nt * 16] = f2fp8(acc[mt][nt][r] * dv);
        }
    }
}

// ---------------- aggregate + relu + fused mean-pool (fp8, padded lists) --------
// Every node list is a multiple of 8 (sentinels -> zero row): uniform 8-deep MLP,
// no tail code. Group start reconstructed from bbase at bucket boundaries.
__global__ __launch_bounds__(256) void agg_pool_kernel(const unsigned* __restrict__ g32,
                                                       const int* __restrict__ rowend,
                                                       const int* __restrict__ csrcol,
                                                       const int* __restrict__ bbase,
                                                       const float* __restrict__ dinv,
                                                       const float* __restrict__ b1,
                                                       const int* __restrict__ batch,
                                                       float* __restrict__ sums) {
    const int lane = threadIdx.x & 63;
    const int wid = threadIdx.x >> 6;
    const int c4 = lane * 4;
    const int nodeA = blockIdx.x * NODES_PER_BLOCK + wid * NODES_PER_GROUP;
    const float4 bv = *(const float4*)&b1[c4];

    int rprev;
    if ((nodeA & 255) == 0) {
        int b = nodeA >> 8;
        rprev = bbase[b] + b * PADSLACK;        // bucket region start
    } else {
        rprev = rowend[nodeA - 1];
    }

    float4 pool = make_float4(0.f, 0.f, 0.f, 0.f);
    int curb = -1;
    #pragma unroll 1
    for (int i = nodeA; i < nodeA + NODES_PER_GROUP; i++) {
        int r1 = rowend[i];
        int r0 = rprev;
        rprev = r1;
        int bi = batch[i];
        if (bi != curb) {
            if (curb >= 0) {
                atomicAdd(&sums[curb * C + c4 + 0], pool.x);
                atomicAdd(&sums[curb * C + c4 + 1], pool.y);
                atomicAdd(&sums[curb * C + c4 + 2], pool.z);
                atomicAdd(&sums[curb * C + c4 + 3], pool.w);
            }
            curb = bi;
            pool = make_float4(0.f, 0.f, 0.f, 0.f);
        }
        float4 s = make_float4(0.f, 0.f, 0.f, 0.f);
        acc_fp8x4(s, g32[(size_t)i * 64 + lane]);     // self-loop term
        #pragma unroll 1
        for (int e = r0; e < r1; e += 8) {
            int i0 = csrcol[e],     i1 = csrcol[e + 1];
            int i2 = csrcol[e + 2], i3 = csrcol[e + 3];
            int i4 = csrcol[e + 4], i5 = csrcol[e + 5];
            int i6 = csrcol[e + 6], i7 = csrcol[e + 7];
            unsigned v0 = g32[(size_t)i0 * 64 + lane];
            unsigned v1 = g32[(size_t)i1 * 64 + lane];
            unsigned v2 = g32[(size_t)i2 * 64 + lane];
            unsigned v3 = g32[(size_t)i3 * 64 + lane];
            unsigned v4 = g32[(size_t)i4 * 64 + lane];
            unsigned v5 = g32[(size_t)i5 * 64 + lane];
            unsigned v6 = g32[(size_t)i6 * 64 + lane];
            unsigned v7 = g32[(size_t)i7 * 64 + lane];
            acc_fp8x4(s, v0); acc_fp8x4(s, v1); acc_fp8x4(s, v2); acc_fp8x4(s, v3);
            acc_fp8x4(s, v4); acc_fp8x4(s, v5); acc_fp8x4(s, v6); acc_fp8x4(s, v7);
        }
        float dv = dinv[i];
        pool.x += fmaxf(fmaf(dv, s.x, bv.x), 0.f);
        pool.y += fmaxf(fmaf(dv, s.y, bv.y), 0.f);
        pool.z += fmaxf(fmaf(dv, s.z, bv.z), 0.f);
        pool.w += fmaxf(fmaf(dv, s.w, bv.w), 0.f);
    }
    if (curb >= 0) {
        atomicAdd(&sums[curb * C + c4 + 0], pool.x);
        atomicAdd(&sums[curb * C + c4 + 1], pool.y);
        atomicAdd(&sums[curb * C + c4 + 2], pool.z);
        atomicAdd(&sums[curb * C + c4 + 3], pool.w);
    }
}

// ---------------- pooled = sums/cnt; out = pooled @ W2 + b2 ----------------
__global__ __launch_bounds__(256) void final_kernel(const float* __restrict__ sums,
                                                    const float* __restrict__ cnt,
                                                    const float* __restrict__ W2,
                                                    const float* __restrict__ b2,
                                                    float* __restrict__ out) {
    __shared__ float p[C];
    int gi = blockIdx.x;
    float cdiv = fmaxf(cnt[gi], 1.0f);
    p[threadIdx.x] = sums[gi * C + threadIdx.x] / cdiv;
    __syncthreads();
    if (threadIdx.x < OUTC) {
        float acc = b2[threadIdx.x];
        for (int k = 0; k < C; k++) acc += p[k] * W2[k * OUTC + threadIdx.x];
        out[gi * OUTC + threadIdx.x] = acc;
    }
}

extern "C" void kernel_launch(void* const* d_in, const int* in_sizes, int n_in,
                              void* d_out, int out_size, void* d_ws, size_t ws_size,
                              hipStream_t stream) {
    const float* x     = (const float*)d_in[0];
    const int*   ei    = (const int*)d_in[1];
    const int*   batch = (const int*)d_in[2];
    const float* W1    = (const float*)d_in[3];
    const float* b1    = (const float*)d_in[4];
    const float* W2    = (const float*)d_in[5];
    const float* b2    = (const float*)d_in[6];
    float* out = (float*)d_out;

    char* w = (char*)d_ws;
    size_t off = 0;
    auto carve = [&](size_t bytes) {
        void* p = w + off;
        off = (off + bytes + 255) & ~(size_t)255;
        return p;
    };
    uchar*    g        = (uchar*)   carve((size_t)(NN + 1) * C);  // fp8 + sentinel row
    int*      rowend   = (int*)     carve((size_t)NN * 4);
    float*    dinv     = (float*)   carve((size_t)NN * 4);
    int*      csrcol   = (int*)     carve((size_t)(EE + NBK * PADSLACK) * 4);
    unsigned* bmaj     = (unsigned*)carve((size_t)EE * 4);
    int*      bbase    = (int*)     carve((size_t)(NBK + 1) * 4);
    int*      bcur     = (int*)     carve((size_t)NBK * 4);
    ushort*   w1f      = (ushort*)  carve((size_t)C * C * 2);
    // contiguous zero-init region:
    int*      bhist    = (int*)     carve((size_t)NBK * 4);
    float*    sums     = (float*)   carve((size_t)NG * C * 4);
    float*    cnt      = (float*)   carve((size_t)NG * 4);
    size_t zero_bytes = (size_t)((char*)cnt + (size_t)NG * 4 - (char*)bhist);

    hipMemsetAsync(bhist, 0, zero_bytes, stream);

    bucket_hist_kernel<<<NBLK1, 256, 0, stream>>>(ei, bhist);
    bucket_scan_kernel<<<1, 512, 0, stream>>>(bhist, bbase, bcur);
    bucket_scatter_kernel<<<NBLK1, 256, 0, stream>>>(ei, bcur, bmaj);
    bucket_csr_kernel<<<NBK, 256, 0, stream>>>(bmaj, bbase, rowend, dinv, csrcol);
    count_kernel<<<(NN + 1023) / 1024, 1024, 0, stream>>>(batch, cnt);
    w1pack_kernel<<<C * C / 256, 256, 0, stream>>>(W1, w1f, (unsigned*)(g + (size_t)NN * C));
    gemm_mfma_kernel<<<(NN / 32 + 3) / 4, 256, 0, stream>>>(x, w1f, dinv, g);
    agg_pool_kernel<<<NN / NODES_PER_BLOCK, 256, 0, stream>>>(
        (const unsigned*)g, rowend, csrcol, bbase, dinv, b1, batch, sums);
    final_kernel<<<NG, 256, 0, stream>>>(sums, cnt, W2, b2, out);
}